// Round 1
// baseline (983.265 us; speedup 1.0000x reference)
//
#include <hip/hip_runtime.h>
#include <hip/hip_bf16.h>

typedef unsigned short u16;
typedef unsigned int   u32;

#define COUT 128
#define KNB  27

typedef __attribute__((ext_vector_type(8))) __bf16 bf16x8;
typedef __attribute__((ext_vector_type(4))) float  f32x4;

// Stats / BN params / dtype flags / bf16 weights in device globals.
// NOTE: device symbols must NEVER be passed as host-side kernel args
// (host shadow address != device address -> GPU fault). Select via template.
__device__ float g_sum[2][128], g_sq[2][128];
__device__ float g_colsum[64], g_G[4096];
__device__ float g_sc[3][128], g_sh[3][128];
__device__ int   g_f32;   // 1 if float input tensors are fp32, 0 if bf16
__device__ int   g_i64;   // 1 if nbr is int64 (read as int32 pairs)
__device__ u16   g_W1t[KNB * 128 * 64];   // [k][d][c] bf16
__device__ u16   g_W2t[KNB * 128 * 128];  // [k][d][c] bf16

__device__ __forceinline__ float b2f(u32 u) {
    union { float f; u32 i; } v; v.i = u << 16; return v.f;
}
__device__ __forceinline__ u16 f2b(float f) {
    union { float f; u32 i; } v; v.f = f;
    u32 r = v.i + 0x7fffu + ((v.i >> 16) & 1u);
    return (u16)(r >> 16);
}
__device__ __forceinline__ float ldf(const void* p, int i, bool f32) {
    return f32 ? ((const float*)p)[i] : b2f((u32)((const u16*)p)[i]);
}

// Raw LDS-only barrier: waits own ds ops, does NOT drain vmcnt, so global
// prefetch loads stay in flight across it (the whole point of the pipeline).
__device__ __forceinline__ void lds_sync() {
    asm volatile("s_waitcnt lgkmcnt(0)" ::: "memory");
    __builtin_amdgcn_s_barrier();
    asm volatile("" ::: "memory");
}

__global__ void probe_zero_kernel(const u16* __restrict__ g1w, const int* __restrict__ nbr)
{
    int t = threadIdx.x;
    if (t == 0) {
        g_f32 = (g1w[0] == 0) ? 1 : 0;   // fp32 1.0f low word == 0
        g_i64 = ((nbr[1] | nbr[3] | nbr[5] | nbr[7]) == 0) ? 1 : 0;
    }
    for (int i = t; i < 128; i += 256) {
        g_sum[0][i] = 0.f; g_sq[0][i] = 0.f;
        g_sum[1][i] = 0.f; g_sq[1][i] = 0.f;
    }
    for (int i = t; i < 64; i += 256) g_colsum[i] = 0.f;
    for (int i = t; i < 4096; i += 256) g_G[i] = 0.f;
}

// Transpose+convert W1/W2 (fp32 or bf16 [k][c][d]) -> bf16 [k][d][c] globals,
// and convert x -> bf16 row-major scratch (so conv1 staging is a pure copy).
__global__ void convert_w_kernel(const void* __restrict__ W1, const void* __restrict__ W2,
                                 const void* __restrict__ x, u16* __restrict__ xb, int N)
{
    const bool f32 = (g_f32 != 0);
    const int total1 = KNB * 64 * 128;
    const int total2 = KNB * 128 * 128;
    const int stride = gridDim.x * 256;
    for (int e = blockIdx.x * 256 + threadIdx.x; e < total1 + total2; e += stride) {
        if (e < total1) {
            int k = e / (64 * 128), r = e % (64 * 128);
            int c = r / 128, d = r % 128;
            g_W1t[(k * 128 + d) * 64 + c] = f2b(ldf(W1, e, f32));
        } else {
            int e2 = e - total1;
            int k = e2 / (128 * 128), r = e2 % (128 * 128);
            int c = r / 128, d = r % 128;
            g_W2t[(k * 128 + d) * 128 + c] = f2b(ldf(W2, e2, f32));
        }
    }
    const int totalx4 = (N * 64) / 4;
    for (int e = blockIdx.x * 256 + threadIdx.x; e < totalx4; e += stride) {
        if (f32) {
            float4 v = ((const float4*)x)[e];
            ushort4 r;
            r.x = f2b(v.x); r.y = f2b(v.y); r.z = f2b(v.z); r.w = f2b(v.w);
            ((ushort4*)xb)[e] = r;
        } else {
            ((uint2*)xb)[e] = ((const uint2*)x)[e];
        }
    }
}

// MFMA gather-conv, depth-2 software pipeline:
//   step s consumes reg-set (s&1) -> LDS buf (s&1), issues loads for s+2
//   into the same reg-set; ONE raw lds_sync per step (no vmcnt drain).
// Neighbor indices are loaded per-thread (4 dwords/k, L1-resident) and
// pipelined one k ahead. Block = 128 rows x 128 cols, 4 waves in 2x2 tile
// split (4 mtiles x 4 ntiles each -> 16 ds_read_b128/step).
// BN+ReLU of the previous layer fused into A-staging (BN_SEL>=0);
// per-column sum/sumsq of the output fused into the epilogue (SSEL>=0).
template<int CIN, int BN_SEL, bool OUTF32, int WSEL, int SSEL>
__global__ __launch_bounds__(256, 2)
void spconv_mfma(const u16* __restrict__ src, const int* __restrict__ nbr,
                 void* __restrict__ outv, int N)
{
    constexpr int NCHUNK = CIN / 64;
    constexpr int STEPS  = KNB * NCHUNK;
    const u16* __restrict__ Wt = (WSEL == 1) ? g_W1t : g_W2t;

    __shared__ u16 As[2 * 8192];   // 2 x (8 mtiles x 2 ksteps x 512) = 32KB
    __shared__ u16 Bs[2 * 8192];   // 32KB

    const int t    = threadIdx.x;
    const int lane = t & 63;
    const int w    = t >> 6;
    const int m    = t & 15;           // staging row-within-tile
    const int q4   = (t >> 4) & 3;     // staging 16B column sub-slice
    const int s_st = w >> 1;           // staging kstep handled by this wave
    const int par  = w & 1;            // staging tile parity
    const int wm   = w >> 1;           // MFMA row-half (mtiles wm*4..+3)
    const int wn   = w & 1;            // MFMA col-half (ntiles wn*4..+3)
    const int n0   = blockIdx.x * 128;
    const int coff = (s_st * 4 + q4) * 8;   // channel offset within 64-chunk
    const int kst  = (g_i64 != 0) ? 2 : 1;  // nbr element stride (int32 units)

    // per-thread A-rows / B-rows (d == r pattern) and nbr offsets
    size_t nboff[4];
    const u16* wptr[4];
#pragma unroll
    for (int i = 0; i < 4; ++i) {
        int r   = (2 * i + par) * 16 + m;
        int gr  = n0 + r;
        int grc = (gr < N) ? gr : (N - 1);
        nboff[i] = (size_t)grc * KNB * kst;
        wptr[i]  = Wt + (size_t)r * CIN + coff;
    }

    float bsc0[8], bsh0[8], bsc1[8], bsh1[8];
    if constexpr (BN_SEL >= 0) {
#pragma unroll
        for (int j = 0; j < 8; ++j) {
            bsc0[j] = g_sc[BN_SEL][coff + j];
            bsh0[j] = g_sh[BN_SEL][coff + j];
        }
        if constexpr (NCHUNK == 2) {
#pragma unroll
            for (int j = 0; j < 8; ++j) {
                bsc1[j] = g_sc[BN_SEL][64 + coff + j];
                bsh1[j] = g_sh[BN_SEL][64 + coff + j];
            }
        }
    }

    f32x4 acc[4][4];
#pragma unroll
    for (int a = 0; a < 4; ++a)
#pragma unroll
        for (int b = 0; b < 4; ++b) acc[a][b] = (f32x4){0.f, 0.f, 0.f, 0.f};

    uint4 a0[4], b0[4], a1[4], b1[4];   // two prefetch register sets
    int idxA[4], idxN[4];

#define LOAD_IDX(K) do { \
    _Pragma("unroll") \
    for (int i_ = 0; i_ < 4; ++i_) \
        idxN[i_] = nbr[nboff[i_] + (size_t)(K) * kst]; \
} while (0)

#define ISSUE_A(AR, IDX, C0N) do { \
    _Pragma("unroll") \
    for (int i_ = 0; i_ < 4; ++i_) { \
        u32 rw_ = (u32)(IDX)[i_]; if (rw_ >= (u32)N) rw_ = 0; \
        AR[i_] = *(const uint4*)(src + (size_t)rw_ * CIN + (C0N) + coff); \
    } \
} while (0)

#define ISSUE_B(BR, K1, C0N) do { \
    _Pragma("unroll") \
    for (int i_ = 0; i_ < 4; ++i_) \
        BR[i_] = *(const uint4*)(wptr[i_] + (size_t)(K1) * (128 * CIN) + (C0N)); \
} while (0)

#define WRITE_AB(AR, BR, LOFS, BSC, BSH) do { \
    _Pragma("unroll") \
    for (int i_ = 0; i_ < 4; ++i_) { \
        const int tile_ = 2 * i_ + par; \
        uint4 pk_; \
        if constexpr (BN_SEL >= 0) { \
            uint4 u_ = AR[i_]; \
            float v0_ = b2f(u_.x & 0xffffu), v1_ = b2f(u_.x >> 16); \
            float v2_ = b2f(u_.y & 0xffffu), v3_ = b2f(u_.y >> 16); \
            float v4_ = b2f(u_.z & 0xffffu), v5_ = b2f(u_.z >> 16); \
            float v6_ = b2f(u_.w & 0xffffu), v7_ = b2f(u_.w >> 16); \
            v0_ = fmaxf(fmaf(v0_, BSC[0], BSH[0]), 0.f); \
            v1_ = fmaxf(fmaf(v1_, BSC[1], BSH[1]), 0.f); \
            v2_ = fmaxf(fmaf(v2_, BSC[2], BSH[2]), 0.f); \
            v3_ = fmaxf(fmaf(v3_, BSC[3], BSH[3]), 0.f); \
            v4_ = fmaxf(fmaf(v4_, BSC[4], BSH[4]), 0.f); \
            v5_ = fmaxf(fmaf(v5_, BSC[5], BSH[5]), 0.f); \
            v6_ = fmaxf(fmaf(v6_, BSC[6], BSH[6]), 0.f); \
            v7_ = fmaxf(fmaf(v7_, BSC[7], BSH[7]), 0.f); \
            pk_.x = (u32)f2b(v0_) | ((u32)f2b(v1_) << 16); \
            pk_.y = (u32)f2b(v2_) | ((u32)f2b(v3_) << 16); \
            pk_.z = (u32)f2b(v4_) | ((u32)f2b(v5_) << 16); \
            pk_.w = (u32)f2b(v6_) | ((u32)f2b(v7_) << 16); \
        } else { \
            pk_ = AR[i_]; \
        } \
        *(uint4*)&As[(LOFS) + (tile_ * 2 + s_st) * 512 + lane * 8] = pk_; \
        *(uint4*)&Bs[(LOFS) + (tile_ * 2 + s_st) * 512 + lane * 8] = BR[i_]; \
    } \
} while (0)

#define MFMA_PHASE(LOFS) do { \
    _Pragma("unroll") \
    for (int s2_ = 0; s2_ < 2; ++s2_) { \
        bf16x8 afr_[4]; \
        _Pragma("unroll") \
        for (int mt_ = 0; mt_ < 4; ++mt_) \
            afr_[mt_] = *(const bf16x8*)&As[(LOFS) + (((wm * 4 + mt_) * 2 + s2_) * 512) + lane * 8]; \
        _Pragma("unroll") \
        for (int nt_ = 0; nt_ < 4; ++nt_) { \
            bf16x8 bfr_ = *(const bf16x8*)&Bs[(LOFS) + (((wn * 4 + nt_) * 2 + s2_) * 512) + lane * 8]; \
            _Pragma("unroll") \
            for (int mt_ = 0; mt_ < 4; ++mt_) \
                acc[mt_][nt_] = __builtin_amdgcn_mfma_f32_16x16x32_bf16( \
                    afr_[mt_], bfr_, acc[mt_][nt_], 0, 0, 0); \
        } \
    } \
} while (0)

    // ---- prologue: fill both register sets, prime the idx pipeline
#pragma unroll
    for (int i = 0; i < 4; ++i) idxA[i] = nbr[nboff[i]];       // k = 0
    ISSUE_A(a0, idxA, 0);
    ISSUE_B(b0, 0, 0);
    if constexpr (NCHUNK == 2) {
        ISSUE_A(a1, idxA, 64);      // step 1 is (k=0, chunk 1)
        ISSUE_B(b1, 0, 64);
        LOAD_IDX(1);                // idxN <- k=1 (for steps 2,3)
    } else {
        LOAD_IDX(1);
        ISSUE_A(a1, idxN, 0);       // step 1 = k=1
        ISSUE_B(b1, 1, 0);
        LOAD_IDX(2);                // idxN <- k=2
    }

    // ---- main loop, unrolled by 2 (named reg sets, static indexing)
    for (int s = 0; s < STEPS; s += 2) {
        // even step s
        WRITE_AB(a0, b0, 0, bsc0, bsh0);
        {
            int s2 = s + 2;
            if (s2 < STEPS) {
                int k2 = (NCHUNK == 2) ? (s2 >> 1) : s2;
                ISSUE_A(a0, idxN, 0);
                ISSUE_B(b0, k2, 0);
            }
            if constexpr (NCHUNK == 1) {
                int k3 = s + 3;
                if (k3 < KNB) LOAD_IDX(k3);
            }
        }
        lds_sync();
        MFMA_PHASE(0);

        // odd step s+1
        if ((NCHUNK == 2) || (s + 1 < STEPS)) {
            WRITE_AB(a1, b1, 8192, bsc1, bsh1);
            {
                int s2 = s + 3;
                if (s2 < STEPS) {
                    int k2 = (NCHUNK == 2) ? (s2 >> 1) : s2;
                    ISSUE_A(a1, idxN, (NCHUNK == 2) ? 64 : 0);
                    ISSUE_B(b1, k2, (NCHUNK == 2) ? 64 : 0);
                }
                int k3 = (NCHUNK == 2) ? ((s >> 1) + 2) : (s + 4);
                if (k3 < KNB) LOAD_IDX(k3);
            }
            lds_sync();
            MFMA_PHASE(8192);
        }
    }

    // ---- epilogue: C/D layout col=lane&15, row=(lane>>4)*4+reg
    const int qq = lane >> 4, nn = lane & 15;
#pragma unroll
    for (int mt = 0; mt < 4; ++mt) {
#pragma unroll
        for (int r4 = 0; r4 < 4; ++r4) {
            int gr = n0 + (wm * 4 + mt) * 16 + qq * 4 + r4;
            if (gr < N) {
#pragma unroll
                for (int nt = 0; nt < 4; ++nt) {
                    float val = acc[mt][nt][r4];
                    size_t off = (size_t)gr * COUT + (wn * 4 + nt) * 16 + nn;
                    if constexpr (OUTF32) ((float*)outv)[off] = val;
                    else                  ((u16*)outv)[off]   = f2b(val);
                }
            }
        }
    }

    // ---- fused per-column BN stats (sum, sumsq) of this block's output
    if constexpr (SSEL >= 0) {
        float sS[4], sQ[4];
#pragma unroll
        for (int nt = 0; nt < 4; ++nt) { sS[nt] = 0.f; sQ[nt] = 0.f; }
#pragma unroll
        for (int mt = 0; mt < 4; ++mt) {
#pragma unroll
            for (int r4 = 0; r4 < 4; ++r4) {
                int gr = n0 + (wm * 4 + mt) * 16 + qq * 4 + r4;
                bool ok = (gr < N);
#pragma unroll
                for (int nt = 0; nt < 4; ++nt) {
                    float v = ok ? acc[mt][nt][r4] : 0.f;
                    sS[nt] += v;
                    sQ[nt] = fmaf(v, v, sQ[nt]);
                }
            }
        }
#pragma unroll
        for (int nt = 0; nt < 4; ++nt) {    // reduce over q = lane>>4
            sS[nt] += __shfl_xor(sS[nt], 16);
            sS[nt] += __shfl_xor(sS[nt], 32);
            sQ[nt] += __shfl_xor(sQ[nt], 16);
            sQ[nt] += __shfl_xor(sQ[nt], 32);
        }
        lds_sync();                         // all MFMA LDS reads done; reuse As
        float* red = (float*)As;            // [4 waves][64 cols] S, then Q
        if (lane < 16) {
#pragma unroll
            for (int nt = 0; nt < 4; ++nt) {
                red[w * 64 + nt * 16 + lane]       = sS[nt];
                red[256 + w * 64 + nt * 16 + lane] = sQ[nt];
            }
        }
        lds_sync();
        if (t < 128) {
            int hi = t >> 6, lo = t & 63;   // waves {hi, hi+2} cover cols hi*64..
            float S = red[hi * 64 + lo] + red[(hi + 2) * 64 + lo];
            float Q = red[256 + hi * 64 + lo] + red[256 + (hi + 2) * 64 + lo];
            atomicAdd(&g_sum[SSEL][t], S);
            atomicAdd(&g_sq[SSEL][t],  Q);
        }
    }
#undef LOAD_IDX
#undef ISSUE_A
#undef ISSUE_B
#undef WRITE_AB
#undef MFMA_PHASE
}

template<int SEL>
__global__ void finalize_kernel(const void* __restrict__ g, const void* __restrict__ b,
                                float invN)
{
    const bool f32 = (g_f32 != 0);
    int c = threadIdx.x;
    float mu  = g_sum[SEL][c] * invN;
    float var = fmaxf(g_sq[SEL][c] * invN - mu * mu, 0.f);
    float rs  = rsqrtf(var + 1e-5f);
    float sc  = rs * ldf(g, c, f32);
    g_sc[SEL][c] = sc;
    g_sh[SEL][c] = ldf(b, c, f32) - mu * sc;
}

// Gram stats of x: G = X^T X (64x64), colsum = sum_n x[n,:]
__global__ __launch_bounds__(256)
void xstats_kernel(const void* __restrict__ xv, int N)
{
    __shared__ float xs[16 * 64];
    const bool f32 = (g_f32 != 0);
    const int t  = threadIdx.x;
    const int c  = t >> 2;
    const int cb = (t & 3) * 16;
    float acc[16];
#pragma unroll
    for (int j = 0; j < 16; ++j) acc[j] = 0.f;
    float cs = 0.f;

    for (int r0 = blockIdx.x * 16; r0 < N; r0 += gridDim.x * 16) {
        __syncthreads();
        {
            int e = t * 4;
            int rr = e >> 6, qq = e & 63;
            int row = r0 + rr;
            size_t off = (size_t)min(row, N - 1) * 64 + qq;
            bool ok = (row < N);
            float v0, v1, v2, v3;
            if (f32) {
                float4 vv = *(const float4*)((const float*)xv + off);
                v0 = vv.x; v1 = vv.y; v2 = vv.z; v3 = vv.w;
            } else {
                uint2 u = *(const uint2*)((const u16*)xv + off);
                v0 = b2f(u.x & 0xffffu); v1 = b2f(u.x >> 16);
                v2 = b2f(u.y & 0xffffu); v3 = b2f(u.y >> 16);
            }
            xs[e + 0] = ok ? v0 : 0.f;
            xs[e + 1] = ok ? v1 : 0.f;
            xs[e + 2] = ok ? v2 : 0.f;
            xs[e + 3] = ok ? v3 : 0.f;
        }
        __syncthreads();
#pragma unroll
        for (int rr = 0; rr < 16; ++rr) {
            float a = xs[rr * 64 + c];
#pragma unroll
            for (int j = 0; j < 16; ++j)
                acc[j] = fmaf(a, xs[rr * 64 + cb + j], acc[j]);
        }
        if (t < 64) {
#pragma unroll
            for (int rr = 0; rr < 16; ++rr) cs += xs[rr * 64 + t];
        }
    }
#pragma unroll
    for (int j = 0; j < 16; ++j) atomicAdd(&g_G[c * 64 + cb + j], acc[j]);
    if (t < 64) atomicAdd(&g_colsum[t], cs);
}

__global__ __launch_bounds__(128)
void finalize_d_kernel(const void* __restrict__ Wd, const void* __restrict__ gd,
                       const void* __restrict__ bd, float invN)
{
    __shared__ float Gs[64 * 64];
    const bool f32 = (g_f32 != 0);
    const int t = threadIdx.x;
    for (int e = t; e < 4096; e += 128) Gs[e] = g_G[e];
    __syncthreads();
    float w[64];
#pragma unroll
    for (int c = 0; c < 64; ++c) w[c] = ldf(Wd, c * 128 + t, f32);
    float s = 0.f, q = 0.f;
    for (int c = 0; c < 64; ++c) {
        float inner = 0.f;
#pragma unroll 8
        for (int cc = 0; cc < 64; ++cc) inner = fmaf(Gs[c * 64 + cc], w[cc], inner);
        q = fmaf(w[c], inner, q);
        s = fmaf(g_colsum[c], w[c], s);
    }
    float mu  = s * invN;
    float var = fmaxf(q * invN - mu * mu, 0.f);
    float rs  = rsqrtf(var + 1e-5f);
    float sc  = rs * ldf(gd, t, f32);
    g_sc[2][t] = sc;
    g_sh[2][t] = ldf(bd, t, f32) - mu * sc;
}

// out = relu(bn2(out)) + bn_d(x @ Wd), fp32 in/out on d_out
__global__ __launch_bounds__(256)
void finish_dense_kernel(const void* __restrict__ xv, const void* __restrict__ Wdv,
                         float* __restrict__ out, int N)
{
    __shared__ float Xs[64 * 68];
    __shared__ float Ws[64 * COUT];
    const bool f32 = (g_f32 != 0);
    const int t  = threadIdx.x;
    const int tx = t & 31;
    const int ty = t >> 5;
    const int n0 = blockIdx.x * 64;
    const int valid = min(64, N - n0);

    for (int e = t; e < 64 * 16; e += 256) {
        int mm = e >> 4;
        int qq = (e & 15) << 2;
        size_t off = (size_t)min(n0 + mm, N - 1) * 64 + qq;
        float v0, v1, v2, v3;
        if (f32) {
            float4 vv = *(const float4*)((const float*)xv + off);
            v0 = vv.x; v1 = vv.y; v2 = vv.z; v3 = vv.w;
        } else {
            uint2 u = *(const uint2*)((const u16*)xv + off);
            v0 = b2f(u.x & 0xffffu); v1 = b2f(u.x >> 16);
            v2 = b2f(u.y & 0xffffu); v3 = b2f(u.y >> 16);
        }
        *(float4*)&Xs[mm * 68 + qq] = make_float4(v0, v1, v2, v3);
    }
    if (f32) {
        const float* Wp = (const float*)Wdv;
        for (int e = t; e < (64 * COUT) / 8; e += 256) {
            int l = e << 3;
            float4 a = *(const float4*)(Wp + l);
            float4 b = *(const float4*)(Wp + l + 4);
            float* dst = &Ws[l];
            dst[0]=a.x; dst[1]=a.y; dst[2]=a.z; dst[3]=a.w;
            dst[4]=b.x; dst[5]=b.y; dst[6]=b.z; dst[7]=b.w;
        }
    } else {
        const u16* Wp = (const u16*)Wdv;
        for (int e = t; e < (64 * COUT) / 8; e += 256) {
            int l = e << 3;
            uint4 u = *(const uint4*)(Wp + l);
            float* dst = &Ws[l];
            dst[0] = b2f(u.x & 0xffffu); dst[1] = b2f(u.x >> 16);
            dst[2] = b2f(u.y & 0xffffu); dst[3] = b2f(u.y >> 16);
            dst[4] = b2f(u.z & 0xffffu); dst[5] = b2f(u.z >> 16);
            dst[6] = b2f(u.w & 0xffffu); dst[7] = b2f(u.w >> 16);
        }
    }
    __syncthreads();

    float acc[8][4];
#pragma unroll
    for (int mm = 0; mm < 8; ++mm)
#pragma unroll
        for (int j = 0; j < 4; ++j) acc[mm][j] = 0.f;

#pragma unroll 2
    for (int c = 0; c < 64; ++c) {
        float4 wv = *(const float4*)&Ws[c * COUT + tx * 4];
#pragma unroll
        for (int mm = 0; mm < 8; ++mm) {
            float a = Xs[(ty * 8 + mm) * 68 + c];
            acc[mm][0] = fmaf(a, wv.x, acc[mm][0]);
            acc[mm][1] = fmaf(a, wv.y, acc[mm][1]);
            acc[mm][2] = fmaf(a, wv.z, acc[mm][2]);
            acc[mm][3] = fmaf(a, wv.w, acc[mm][3]);
        }
    }

    const int d = tx * 4;
    float s2r[4] = {g_sc[1][d], g_sc[1][d+1], g_sc[1][d+2], g_sc[1][d+3]};
    float h2r[4] = {g_sh[1][d], g_sh[1][d+1], g_sh[1][d+2], g_sh[1][d+3]};
    float sdr[4] = {g_sc[2][d], g_sc[2][d+1], g_sc[2][d+2], g_sc[2][d+3]};
    float hdr[4] = {g_sh[2][d], g_sh[2][d+1], g_sh[2][d+2], g_sh[2][d+3]};
#pragma unroll
    for (int mm = 0; mm < 8; ++mm) {
        int rr = ty * 8 + mm;
        if (rr < valid) {
            float* p = out + (size_t)(n0 + rr) * COUT + d;
            float4 raw = *(float4*)p;
            float o0 = fmaxf(fmaf(raw.x, s2r[0], h2r[0]), 0.f) + fmaf(acc[mm][0], sdr[0], hdr[0]);
            float o1 = fmaxf(fmaf(raw.y, s2r[1], h2r[1]), 0.f) + fmaf(acc[mm][1], sdr[1], hdr[1]);
            float o2 = fmaxf(fmaf(raw.z, s2r[2], h2r[2]), 0.f) + fmaf(acc[mm][2], sdr[2], hdr[2]);
            float o3 = fmaxf(fmaf(raw.w, s2r[3], h2r[3]), 0.f) + fmaf(acc[mm][3], sdr[3], hdr[3]);
            *(float4*)p = make_float4(o0, o1, o2, o3);
        }
    }
}

extern "C" void kernel_launch(void* const* d_in, const int* in_sizes, int n_in,
                              void* d_out, int out_size, void* d_ws, size_t ws_size,
                              hipStream_t stream)
{
    const void* x   = d_in[0];
    const int*  nbr = (const int*)d_in[1];
    const void* W1  = d_in[2];
    const void* g1  = d_in[3];
    const void* b1  = d_in[4];
    const void* W2  = d_in[5];
    const void* g2  = d_in[6];
    const void* b2  = d_in[7];
    const void* Wd  = d_in[8];
    const void* gd  = d_in[9];
    const void* bd  = d_in[10];
    float* out = (float*)d_out;

    const int N = in_sizes[0] / 64;
    u16* tmp = (u16*)d_ws;            // [N,128] bf16 conv1 raw — only ws use
    u16* xb  = (u16*)d_out;           // [N,64] bf16 x — scratch in d_out, dead
                                      // before conv2 overwrites d_out

    const int nbm = (N + 127) / 128;  // MFMA conv blocks
    const int nbf = (N + 63) / 64;    // finish blocks
    const float invN = 1.f / (float)N;

    hipLaunchKernelGGL(probe_zero_kernel, dim3(1), dim3(256), 0, stream,
                       (const u16*)g1, nbr);
    hipLaunchKernelGGL(convert_w_kernel, dim3(1024), dim3(256), 0, stream,
                       W1, W2, x, xb, N);
    // conv1 raw -> tmp (bf16), stats fused (SSEL=0)
    hipLaunchKernelGGL((spconv_mfma<64, -1, false, 1, 0>), dim3(nbm), dim3(256), 0, stream,
                       xb, nbr, tmp, N);
    hipLaunchKernelGGL((finalize_kernel<0>), dim3(1), dim3(128), 0, stream, g1, b1, invN);
    // conv2 (bn1+relu fused into A-staging) -> d_out raw fp32, stats fused (SSEL=1)
    hipLaunchKernelGGL((spconv_mfma<128, 0, true, 2, 1>), dim3(nbm), dim3(256), 0, stream,
                       tmp, nbr, out, N);
    hipLaunchKernelGGL((finalize_kernel<1>), dim3(1), dim3(128), 0, stream, g2, b2, invN);
    // dense-branch stats without materializing x@Wd
    hipLaunchKernelGGL(xstats_kernel, dim3(256), dim3(256), 0, stream, x, N);
    hipLaunchKernelGGL(finalize_d_kernel, dim3(1), dim3(128), 0, stream, Wd, gd, bd, invN);
    // out = relu(bn2(out)) + bn_d(x@Wd)
    hipLaunchKernelGGL(finish_dense_kernel, dim3(nbf), dim3(256), 0, stream,
                       x, Wd, out, N);
}

// Round 2
// 811.708 us; speedup vs baseline: 1.2114x; 1.2114x over previous
//
#include <hip/hip_runtime.h>
#include <hip/hip_bf16.h>

typedef unsigned short u16;
typedef unsigned int   u32;

#define COUT 128
#define KNB  27

typedef __attribute__((ext_vector_type(8))) __bf16 bf16x8;
typedef __attribute__((ext_vector_type(4))) float  f32x4;

// Stats / BN params / dtype flags / bf16 weights in device globals.
// NOTE: device symbols must NEVER be passed as host-side kernel args
// (host shadow address != device address -> GPU fault). Select via template.
__device__ float g_sum[2][128], g_sq[2][128];
__device__ float g_colsum[64], g_G[4096];
__device__ float g_sc[3][128], g_sh[3][128];
__device__ int   g_f32;   // 1 if float input tensors are fp32, 0 if bf16
__device__ int   g_i64;   // 1 if nbr is int64 (read as int32 pairs)
__device__ __attribute__((aligned(16))) u16 g_W1t[KNB * 128 * 64];   // [k][d][c] bf16
__device__ __attribute__((aligned(16))) u16 g_W2t[KNB * 128 * 128];  // [k][d][c] bf16

__device__ __forceinline__ float b2f(u32 u) {
    union { float f; u32 i; } v; v.i = u << 16; return v.f;
}
__device__ __forceinline__ u16 f2b(float f) {
    union { float f; u32 i; } v; v.f = f;
    u32 r = v.i + 0x7fffu + ((v.i >> 16) & 1u);
    return (u16)(r >> 16);
}
__device__ __forceinline__ float ldf(const void* p, int i, bool f32) {
    return f32 ? ((const float*)p)[i] : b2f((u32)((const u16*)p)[i]);
}

// async 16B global->LDS (DMA, no VGPR round-trip). LDS dest: wave-uniform
// base; HW writes lane l's 16B at base + l*16. Global src is per-lane.
__device__ __forceinline__ void gld16(const void* g, void* l) {
    __builtin_amdgcn_global_load_lds(
        (const __attribute__((address_space(1))) u32*)g,
        (__attribute__((address_space(3))) u32*)l, 16, 0, 0);
}

// Raw LDS-only barrier: waits own ds ops, does NOT drain vmcnt, so global
// loads stay in flight across it (the whole point of the pipeline).
__device__ __forceinline__ void lds_sync() {
    asm volatile("s_waitcnt lgkmcnt(0)" ::: "memory");
    __builtin_amdgcn_s_barrier();
    asm volatile("" ::: "memory");
}

__global__ void probe_zero_kernel(const u16* __restrict__ g1w, const int* __restrict__ nbr)
{
    int t = threadIdx.x;
    if (t == 0) {
        g_f32 = (g1w[0] == 0) ? 1 : 0;   // fp32 1.0f low word == 0
        g_i64 = ((nbr[1] | nbr[3] | nbr[5] | nbr[7]) == 0) ? 1 : 0;
    }
    for (int i = t; i < 128; i += 256) {
        g_sum[0][i] = 0.f; g_sq[0][i] = 0.f;
        g_sum[1][i] = 0.f; g_sq[1][i] = 0.f;
    }
    for (int i = t; i < 64; i += 256) g_colsum[i] = 0.f;
    for (int i = t; i < 4096; i += 256) g_G[i] = 0.f;
}

// Transpose+convert W1/W2 (fp32 or bf16 [k][c][d]) -> bf16 [k][d][c] globals,
// and convert x -> bf16 row-major scratch (so conv1 staging is a pure copy).
__global__ void convert_w_kernel(const void* __restrict__ W1, const void* __restrict__ W2,
                                 const void* __restrict__ x, u16* __restrict__ xb, int N)
{
    const bool f32 = (g_f32 != 0);
    const int total1 = KNB * 64 * 128;
    const int total2 = KNB * 128 * 128;
    const int stride = gridDim.x * 256;
    for (int e = blockIdx.x * 256 + threadIdx.x; e < total1 + total2; e += stride) {
        if (e < total1) {
            int k = e / (64 * 128), r = e % (64 * 128);
            int c = r / 128, d = r % 128;
            g_W1t[(k * 128 + d) * 64 + c] = f2b(ldf(W1, e, f32));
        } else {
            int e2 = e - total1;
            int k = e2 / (128 * 128), r = e2 % (128 * 128);
            int c = r / 128, d = r % 128;
            g_W2t[(k * 128 + d) * 128 + c] = f2b(ldf(W2, e2, f32));
        }
    }
    const int totalx4 = (N * 64) / 4;
    for (int e = blockIdx.x * 256 + threadIdx.x; e < totalx4; e += stride) {
        if (f32) {
            float4 v = ((const float4*)x)[e];
            ushort4 r;
            r.x = f2b(v.x); r.y = f2b(v.y); r.z = f2b(v.z); r.w = f2b(v.w);
            ((ushort4*)xb)[e] = r;
        } else {
            ((uint2*)xb)[e] = ((const uint2*)x)[e];
        }
    }
}

// In-place bn1+relu on tmp [N][128] bf16 so conv2's A-staging is a pure copy.
__global__ __launch_bounds__(256)
void bn_relu_kernel(u16* __restrict__ tmp, int N)
{
    const int t  = threadIdx.x;
    const int c0 = (t & 15) * 8;          // stride is a multiple of 16 granules
    float sc[8], sh[8];
#pragma unroll
    for (int j = 0; j < 8; ++j) { sc[j] = g_sc[0][c0 + j]; sh[j] = g_sh[0][c0 + j]; }
    const int total = N * (COUT / 8);
    for (int e = blockIdx.x * 256 + t; e < total; e += gridDim.x * 256) {
        uint4 u = ((const uint4*)tmp)[e];
        float v[8] = { b2f(u.x & 0xffffu), b2f(u.x >> 16),
                       b2f(u.y & 0xffffu), b2f(u.y >> 16),
                       b2f(u.z & 0xffffu), b2f(u.z >> 16),
                       b2f(u.w & 0xffffu), b2f(u.w >> 16) };
#pragma unroll
        for (int j = 0; j < 8; ++j) v[j] = fmaxf(fmaf(v[j], sc[j], sh[j]), 0.f);
        uint4 o;
        o.x = (u32)f2b(v[0]) | ((u32)f2b(v[1]) << 16);
        o.y = (u32)f2b(v[2]) | ((u32)f2b(v[3]) << 16);
        o.z = (u32)f2b(v[4]) | ((u32)f2b(v[5]) << 16);
        o.w = (u32)f2b(v[6]) | ((u32)f2b(v[7]) << 16);
        ((uint4*)tmp)[e] = o;
    }
}

// MFMA gather-conv with async global->LDS staging (zero staging VGPRs):
//   per step: issue 8 global_load_lds (4 A-gather + 4 B-weight slabs) for
//   step s+1 into buf[nxt] + 4 nbr-index dword loads for s+2 (one-step reg
//   pipeline); counted s_waitcnt vmcnt(16) drains ONLY step s's loads while
//   s+1's 12 stay in flight across the barrier; then ds_read+MFMA on buf[cur].
// vmcnt ledger (per wave, steady state, oldest->newest at the wait):
//   [gld(s) x8][idx(s+2) x4][gld(s+1) x8][idx(s+3) x4] -> newer-than-gld(s)=16.
// Tail iterations use vmcnt(0) (once, free); loop unroll disabled so DCE of
// tail idx loads can't invalidate the ledger.
// Block: 128 rows x 128 cols; 4 waves, 2x2 output split (4x4 16x16 tiles,
// 64 acc VGPRs/wave). LDS slabs lane-linear -> matches DMA write pattern.
template<int CIN, bool OUTF32, int WSEL, int SSEL>
__global__ __launch_bounds__(256, 2)
void spconv_mfma(const u16* __restrict__ src, const int* __restrict__ nbr,
                 void* __restrict__ outv, int N)
{
    constexpr int NCHUNK = CIN / 64;
    constexpr int STEPS  = KNB * NCHUNK;
    constexpr int OFF_ODD = (NCHUNK == 2) ? 64 : 0;   // chunk offset of odd steps
    const u16* __restrict__ Wt = (WSEL == 1) ? g_W1t : g_W2t;

    __shared__ __attribute__((aligned(16))) u16 As[2 * 8192];  // 2 x 16KB
    __shared__ __attribute__((aligned(16))) u16 Bs[2 * 8192];  // 2 x 16KB

    const int t    = threadIdx.x;
    const int lane = t & 63;
    const int w    = t >> 6;
    const int m    = lane & 15;        // staging row-within-tile
    const int q4   = lane >> 4;        // staging 16B column sub-slice (0..3)
    const int s_st = w >> 1;           // staging kstep handled by this wave
    const int par  = w & 1;            // staging tile parity
    const int wm   = w >> 1;           // MFMA row-half (mtiles wm*4..+3)
    const int wn   = w & 1;            // MFMA col-half (ntiles wn*4..+3)
    const int n0   = blockIdx.x * 128;
    const int coff = (s_st * 4 + q4) * 8;   // channel offset within 64-chunk
    const int kst  = (g_i64 != 0) ? 2 : 1;  // nbr element stride (int32 units)

    // per-lane bases: nbr offset for this thread's 4 A-rows (r = 2i+par tiles)
    u32 nb0[4];
#pragma unroll
    for (int i = 0; i < 4; ++i) {
        int gr  = n0 + (2 * i + par) * 16 + m;
        int grc = (gr < N) ? gr : (N - 1);
        nb0[i] = (u32)grc * (u32)(KNB * kst);
    }

    f32x4 acc[4][4];
#pragma unroll
    for (int a = 0; a < 4; ++a)
#pragma unroll
        for (int b = 0; b < 4; ++b) acc[a][b] = (f32x4){0.f, 0.f, 0.f, 0.f};

    int idxE[4], idxO[4];

#define STEP_K(S)  ((NCHUNK == 2) ? ((S) >> 1) : (S))
#define LOAD_IDX(DST, K) do { \
    int kk_ = (K) < KNB ? (K) : (KNB - 1); \
    _Pragma("unroll") \
    for (int i_ = 0; i_ < 4; ++i_) \
        DST[i_] = nbr[nb0[i_] + (u32)kk_ * (u32)kst]; \
} while (0)

    // 8 async 16B DMAs: A-gather rows + B-weight rows for one step.
#define ISSUE_STEP(BUFO, IDX, K, C0N) do { \
    _Pragma("unroll") \
    for (int i_ = 0; i_ < 4; ++i_) { \
        const int tile_ = 2 * i_ + par; \
        u32 rw_ = (u32)(IDX)[i_]; if (rw_ >= (u32)N) rw_ = 0; \
        gld16(src + (size_t)rw_ * CIN + (C0N) + coff, \
              &As[(BUFO) + (tile_ * 2 + s_st) * 512]); \
        gld16(Wt + ((size_t)(K) * 128 + tile_ * 16 + m) * CIN + (C0N) + coff, \
              &Bs[(BUFO) + (tile_ * 2 + s_st) * 512]); \
    } \
} while (0)

#define MFMA_PHASE(LOFS) do { \
    __builtin_amdgcn_s_setprio(1); \
    _Pragma("unroll") \
    for (int s2_ = 0; s2_ < 2; ++s2_) { \
        bf16x8 afr_[4]; \
        _Pragma("unroll") \
        for (int mt_ = 0; mt_ < 4; ++mt_) \
            afr_[mt_] = *(const bf16x8*)&As[(LOFS) + (((wm * 4 + mt_) * 2 + s2_) * 512) + lane * 8]; \
        _Pragma("unroll") \
        for (int nt_ = 0; nt_ < 4; ++nt_) { \
            bf16x8 bfr_ = *(const bf16x8*)&Bs[(LOFS) + (((wn * 4 + nt_) * 2 + s2_) * 512) + lane * 8]; \
            _Pragma("unroll") \
            for (int mt_ = 0; mt_ < 4; ++mt_) \
                acc[mt_][nt_] = __builtin_amdgcn_mfma_f32_16x16x32_bf16( \
                    afr_[mt_], bfr_, acc[mt_][nt_], 0, 0, 0); \
        } \
    } \
    __builtin_amdgcn_s_setprio(0); \
} while (0)

    // ---- prologue: prime idx pipeline, issue step 0 into buf0
    LOAD_IDX(idxE, 0);                       // idx(step0); consumed right below
    LOAD_IDX(idxO, STEP_K(1));               // idx(step1)
    ISSUE_STEP(0, idxE, 0, 0);               // gld(step0) -> buf0
    LOAD_IDX(idxE, STEP_K(2));               // idx(step2)

    // ---- main loop, manually unrolled x2 (even->buf0, odd->buf1)
#pragma clang loop unroll(disable)
    for (int s = 0; s < STEPS; s += 2) {
        // ===== even step s (consume buf0) =====
        lds_sync();                           // all waves done reading buf1
        if (s + 1 < STEPS) {
            ISSUE_STEP(8192, idxO, STEP_K(s + 1), OFF_ODD);   // gld(s+1)->buf1
            LOAD_IDX(idxO, STEP_K(s + 3));                     // idx(s+3)
            asm volatile("s_waitcnt vmcnt(16)" ::: "memory");  // drain gld(s)
        } else {
            asm volatile("s_waitcnt vmcnt(0)" ::: "memory");   // tail (once)
        }
        __builtin_amdgcn_s_barrier();
        asm volatile("" ::: "memory");
        MFMA_PHASE(0);

        // ===== odd step s+1 (consume buf1) =====
        if (s + 1 < STEPS) {
            lds_sync();                       // all waves done reading buf0
            if (s + 2 < STEPS) {
                ISSUE_STEP(0, idxE, STEP_K(s + 2), 0);         // gld(s+2)->buf0
                LOAD_IDX(idxE, STEP_K(s + 4));                 // idx(s+4)
                asm volatile("s_waitcnt vmcnt(16)" ::: "memory");
            } else {
                asm volatile("s_waitcnt vmcnt(0)" ::: "memory");
            }
            __builtin_amdgcn_s_barrier();
            asm volatile("" ::: "memory");
            MFMA_PHASE(8192);
        }
    }

    // ---- epilogue: C/D layout col=lane&15, row=(lane>>4)*4+reg
    const int qq = lane >> 4, nn = lane & 15;
#pragma unroll
    for (int mt = 0; mt < 4; ++mt) {
#pragma unroll
        for (int r4 = 0; r4 < 4; ++r4) {
            int gr = n0 + (wm * 4 + mt) * 16 + qq * 4 + r4;
            if (gr < N) {
#pragma unroll
                for (int nt = 0; nt < 4; ++nt) {
                    float val = acc[mt][nt][r4];
                    size_t off = (size_t)gr * COUT + (wn * 4 + nt) * 16 + nn;
                    if constexpr (OUTF32) ((float*)outv)[off] = val;
                    else                  ((u16*)outv)[off]   = f2b(val);
                }
            }
        }
    }

    // ---- fused per-column BN stats (sum, sumsq) of this block's output
    if constexpr (SSEL >= 0) {
        float sS[4], sQ[4];
#pragma unroll
        for (int nt = 0; nt < 4; ++nt) { sS[nt] = 0.f; sQ[nt] = 0.f; }
#pragma unroll
        for (int mt = 0; mt < 4; ++mt) {
#pragma unroll
            for (int r4 = 0; r4 < 4; ++r4) {
                int gr = n0 + (wm * 4 + mt) * 16 + qq * 4 + r4;
                bool ok = (gr < N);
#pragma unroll
                for (int nt = 0; nt < 4; ++nt) {
                    float v = ok ? acc[mt][nt][r4] : 0.f;
                    sS[nt] += v;
                    sQ[nt] = fmaf(v, v, sQ[nt]);
                }
            }
        }
#pragma unroll
        for (int nt = 0; nt < 4; ++nt) {    // reduce over q = lane>>4
            sS[nt] += __shfl_xor(sS[nt], 16);
            sS[nt] += __shfl_xor(sS[nt], 32);
            sQ[nt] += __shfl_xor(sQ[nt], 16);
            sQ[nt] += __shfl_xor(sQ[nt], 32);
        }
        lds_sync();                         // all MFMA LDS reads done; reuse As
        float* red = (float*)As;            // [4 waves][64 cols] S, then Q
        if (lane < 16) {
#pragma unroll
            for (int nt = 0; nt < 4; ++nt) {
                red[w * 64 + nt * 16 + lane]       = sS[nt];
                red[256 + w * 64 + nt * 16 + lane] = sQ[nt];
            }
        }
        lds_sync();
        if (t < 128) {
            int hi = t >> 6, lo = t & 63;   // waves {hi, hi+2} cover cols hi*64..
            float S = red[hi * 64 + lo] + red[(hi + 2) * 64 + lo];
            float Q = red[256 + hi * 64 + lo] + red[256 + (hi + 2) * 64 + lo];
            atomicAdd(&g_sum[SSEL][t], S);
            atomicAdd(&g_sq[SSEL][t],  Q);
        }
    }
#undef STEP_K
#undef LOAD_IDX
#undef ISSUE_STEP
#undef MFMA_PHASE
}

template<int SEL>
__global__ void finalize_kernel(const void* __restrict__ g, const void* __restrict__ b,
                                float invN)
{
    const bool f32 = (g_f32 != 0);
    int c = threadIdx.x;
    float mu  = g_sum[SEL][c] * invN;
    float var = fmaxf(g_sq[SEL][c] * invN - mu * mu, 0.f);
    float rs  = rsqrtf(var + 1e-5f);
    float sc  = rs * ldf(g, c, f32);
    g_sc[SEL][c] = sc;
    g_sh[SEL][c] = ldf(b, c, f32) - mu * sc;
}

// Gram stats of x: G = X^T X (64x64), colsum = sum_n x[n,:]
__global__ __launch_bounds__(256)
void xstats_kernel(const void* __restrict__ xv, int N)
{
    __shared__ float xs[16 * 64];
    const bool f32 = (g_f32 != 0);
    const int t  = threadIdx.x;
    const int c  = t >> 2;
    const int cb = (t & 3) * 16;
    float acc[16];
#pragma unroll
    for (int j = 0; j < 16; ++j) acc[j] = 0.f;
    float cs = 0.f;

    for (int r0 = blockIdx.x * 16; r0 < N; r0 += gridDim.x * 16) {
        __syncthreads();
        {
            int e = t * 4;
            int rr = e >> 6, qq = e & 63;
            int row = r0 + rr;
            size_t off = (size_t)min(row, N - 1) * 64 + qq;
            bool ok = (row < N);
            float v0, v1, v2, v3;
            if (f32) {
                float4 vv = *(const float4*)((const float*)xv + off);
                v0 = vv.x; v1 = vv.y; v2 = vv.z; v3 = vv.w;
            } else {
                uint2 u = *(const uint2*)((const u16*)xv + off);
                v0 = b2f(u.x & 0xffffu); v1 = b2f(u.x >> 16);
                v2 = b2f(u.y & 0xffffu); v3 = b2f(u.y >> 16);
            }
            xs[e + 0] = ok ? v0 : 0.f;
            xs[e + 1] = ok ? v1 : 0.f;
            xs[e + 2] = ok ? v2 : 0.f;
            xs[e + 3] = ok ? v3 : 0.f;
        }
        __syncthreads();
#pragma unroll
        for (int rr = 0; rr < 16; ++rr) {
            float a = xs[rr * 64 + c];
#pragma unroll
            for (int j = 0; j < 16; ++j)
                acc[j] = fmaf(a, xs[rr * 64 + cb + j], acc[j]);
        }
        if (t < 64) {
#pragma unroll
            for (int rr = 0; rr < 16; ++rr) cs += xs[rr * 64 + t];
        }
    }
#pragma unroll
    for (int j = 0; j < 16; ++j) atomicAdd(&g_G[c * 64 + cb + j], acc[j]);
    if (t < 64) atomicAdd(&g_colsum[t], cs);
}

__global__ __launch_bounds__(128)
void finalize_d_kernel(const void* __restrict__ Wd, const void* __restrict__ gd,
                       const void* __restrict__ bd, float invN)
{
    __shared__ float Gs[64 * 64];
    const bool f32 = (g_f32 != 0);
    const int t = threadIdx.x;
    for (int e = t; e < 4096; e += 128) Gs[e] = g_G[e];
    __syncthreads();
    float w[64];
#pragma unroll
    for (int c = 0; c < 64; ++c) w[c] = ldf(Wd, c * 128 + t, f32);
    float s = 0.f, q = 0.f;
    for (int c = 0; c < 64; ++c) {
        float inner = 0.f;
#pragma unroll 8
        for (int cc = 0; cc < 64; ++cc) inner = fmaf(Gs[c * 64 + cc], w[cc], inner);
        q = fmaf(w[c], inner, q);
        s = fmaf(g_colsum[c], w[c], s);
    }
    float mu  = s * invN;
    float var = fmaxf(q * invN - mu * mu, 0.f);
    float rs  = rsqrtf(var + 1e-5f);
    float sc  = rs * ldf(gd, t, f32);
    g_sc[2][t] = sc;
    g_sh[2][t] = ldf(bd, t, f32) - mu * sc;
}

// out = relu(bn2(out)) + bn_d(x @ Wd), fp32 in/out on d_out
__global__ __launch_bounds__(256)
void finish_dense_kernel(const void* __restrict__ xv, const void* __restrict__ Wdv,
                         float* __restrict__ out, int N)
{
    __shared__ float Xs[64 * 68];
    __shared__ float Ws[64 * COUT];
    const bool f32 = (g_f32 != 0);
    const int t  = threadIdx.x;
    const int tx = t & 31;
    const int ty = t >> 5;
    const int n0 = blockIdx.x * 64;
    const int valid = min(64, N - n0);

    for (int e = t; e < 64 * 16; e += 256) {
        int mm = e >> 4;
        int qq = (e & 15) << 2;
        size_t off = (size_t)min(n0 + mm, N - 1) * 64 + qq;
        float v0, v1, v2, v3;
        if (f32) {
            float4 vv = *(const float4*)((const float*)xv + off);
            v0 = vv.x; v1 = vv.y; v2 = vv.z; v3 = vv.w;
        } else {
            uint2 u = *(const uint2*)((const u16*)xv + off);
            v0 = b2f(u.x & 0xffffu); v1 = b2f(u.x >> 16);
            v2 = b2f(u.y & 0xffffu); v3 = b2f(u.y >> 16);
        }
        *(float4*)&Xs[mm * 68 + qq] = make_float4(v0, v1, v2, v3);
    }
    if (f32) {
        const float* Wp = (const float*)Wdv;
        for (int e = t; e < (64 * COUT) / 8; e += 256) {
            int l = e << 3;
            float4 a = *(const float4*)(Wp + l);
            float4 b = *(const float4*)(Wp + l + 4);
            float* dst = &Ws[l];
            dst[0]=a.x; dst[1]=a.y; dst[2]=a.z; dst[3]=a.w;
            dst[4]=b.x; dst[5]=b.y; dst[6]=b.z; dst[7]=b.w;
        }
    } else {
        const u16* Wp = (const u16*)Wdv;
        for (int e = t; e < (64 * COUT) / 8; e += 256) {
            int l = e << 3;
            uint4 u = *(const uint4*)(Wp + l);
            float* dst = &Ws[l];
            dst[0] = b2f(u.x & 0xffffu); dst[1] = b2f(u.x >> 16);
            dst[2] = b2f(u.y & 0xffffu); dst[3] = b2f(u.y >> 16);
            dst[4] = b2f(u.z & 0xffffu); dst[5] = b2f(u.z >> 16);
            dst[6] = b2f(u.w & 0xffffu); dst[7] = b2f(u.w >> 16);
        }
    }
    __syncthreads();

    float acc[8][4];
#pragma unroll
    for (int mm = 0; mm < 8; ++mm)
#pragma unroll
        for (int j = 0; j < 4; ++j) acc[mm][j] = 0.f;

#pragma unroll 2
    for (int c = 0; c < 64; ++c) {
        float4 wv = *(const float4*)&Ws[c * COUT + tx * 4];
#pragma unroll
        for (int mm = 0; mm < 8; ++mm) {
            float a = Xs[(ty * 8 + mm) * 68 + c];
            acc[mm][0] = fmaf(a, wv.x, acc[mm][0]);
            acc[mm][1] = fmaf(a, wv.y, acc[mm][1]);
            acc[mm][2] = fmaf(a, wv.z, acc[mm][2]);
            acc[mm][3] = fmaf(a, wv.w, acc[mm][3]);
        }
    }

    const int d = tx * 4;
    float s2r[4] = {g_sc[1][d], g_sc[1][d+1], g_sc[1][d+2], g_sc[1][d+3]};
    float h2r[4] = {g_sh[1][d], g_sh[1][d+1], g_sh[1][d+2], g_sh[1][d+3]};
    float sdr[4] = {g_sc[2][d], g_sc[2][d+1], g_sc[2][d+2], g_sc[2][d+3]};
    float hdr[4] = {g_sh[2][d], g_sh[2][d+1], g_sh[2][d+2], g_sh[2][d+3]};
#pragma unroll
    for (int mm = 0; mm < 8; ++mm) {
        int rr = ty * 8 + mm;
        if (rr < valid) {
            float* p = out + (size_t)(n0 + rr) * COUT + d;
            float4 raw = *(float4*)p;
            float o0 = fmaxf(fmaf(raw.x, s2r[0], h2r[0]), 0.f) + fmaf(acc[mm][0], sdr[0], hdr[0]);
            float o1 = fmaxf(fmaf(raw.y, s2r[1], h2r[1]), 0.f) + fmaf(acc[mm][1], sdr[1], hdr[1]);
            float o2 = fmaxf(fmaf(raw.z, s2r[2], h2r[2]), 0.f) + fmaf(acc[mm][2], sdr[2], hdr[2]);
            float o3 = fmaxf(fmaf(raw.w, s2r[3], h2r[3]), 0.f) + fmaf(acc[mm][3], sdr[3], hdr[3]);
            *(float4*)p = make_float4(o0, o1, o2, o3);
        }
    }
}

extern "C" void kernel_launch(void* const* d_in, const int* in_sizes, int n_in,
                              void* d_out, int out_size, void* d_ws, size_t ws_size,
                              hipStream_t stream)
{
    const void* x   = d_in[0];
    const int*  nbr = (const int*)d_in[1];
    const void* W1  = d_in[2];
    const void* g1  = d_in[3];
    const void* b1  = d_in[4];
    const void* W2  = d_in[5];
    const void* g2  = d_in[6];
    const void* b2  = d_in[7];
    const void* Wd  = d_in[8];
    const void* gd  = d_in[9];
    const void* bd  = d_in[10];
    float* out = (float*)d_out;

    const int N = in_sizes[0] / 64;
    u16* tmp = (u16*)d_ws;            // [N,128] bf16 conv1 raw — only ws use
    u16* xb  = (u16*)d_out;           // [N,64] bf16 x — scratch in d_out, dead
                                      // before conv2 overwrites d_out

    const int nbm = (N + 127) / 128;  // MFMA conv blocks
    const int nbf = (N + 63) / 64;    // finish blocks
    const float invN = 1.f / (float)N;

    hipLaunchKernelGGL(probe_zero_kernel, dim3(1), dim3(256), 0, stream,
                       (const u16*)g1, nbr);
    hipLaunchKernelGGL(convert_w_kernel, dim3(1024), dim3(256), 0, stream,
                       W1, W2, x, xb, N);
    // conv1 raw -> tmp (bf16), stats fused (SSEL=0)
    hipLaunchKernelGGL((spconv_mfma<64, false, 1, 0>), dim3(nbm), dim3(256), 0, stream,
                       xb, nbr, tmp, N);
    hipLaunchKernelGGL((finalize_kernel<0>), dim3(1), dim3(128), 0, stream, g1, b1, invN);
    // apply bn1+relu in place so conv2 staging is a pure async copy
    hipLaunchKernelGGL(bn_relu_kernel, dim3(2048), dim3(256), 0, stream, tmp, N);
    // conv2 -> d_out raw fp32, stats fused (SSEL=1)
    hipLaunchKernelGGL((spconv_mfma<128, true, 2, 1>), dim3(nbm), dim3(256), 0, stream,
                       tmp, nbr, out, N);
    hipLaunchKernelGGL((finalize_kernel<1>), dim3(1), dim3(128), 0, stream, g2, b2, invN);
    // dense-branch stats without materializing x@Wd
    hipLaunchKernelGGL(xstats_kernel, dim3(256), dim3(256), 0, stream, x, N);
    hipLaunchKernelGGL(finalize_d_kernel, dim3(1), dim3(128), 0, stream, Wd, gd, bd, invN);
    // out = relu(bn2(out)) + bn_d(x@Wd)
    hipLaunchKernelGGL(finish_dense_kernel, dim3(nbf), dim3(256), 0, stream,
                       x, Wd, out, N);
}